// Round 11
// baseline (516.159 us; speedup 1.0000x reference)
//
#include <hip/hip_runtime.h>
#include <math.h>

// N=100000 nodes, E=1600000 edges, features 128 -> 64 -> 64 -> 1.
// R32 = R31 with k_gemm2 ELIMINATED: the first agg's epilogue (which holds
// the full ReLU'd h-row of each node in 8 oct0-lanes x 8 f32 regs) computes
// ts2[node][c] = (h @ W2)[c] * dis[node] directly (FUSE2): W2 staged f32 in
// LDS (16KB; 8 blk/CU x 16KB = 128KB <= 160, occupancy kept), 64 iters of
// {shfl h_k within the 8-lane group, 2x ds_read_b128 W2 row slice, 8 FMA}
// ~= +4us epilogue. Output ts2 -> HB (NOT TSB: agg still reads ts1 rows of
// other nodes from TSB -> race if in-place); agg2(FUSE3) reads HB. Numerics
// improve: h pre-bf16-rounding, W2 full f32 (hi/lo split gone). Removes
// gemm2 kernel (~9us) + launch gap (~4.3) + 25MB HB/TSB round trip.
// Launches 9 -> 8. Epilogue-only edit per R29 lesson (FUSE3 proved safe;
// R28's regression was LOOP-BODY edits — gather loop untouched, verbatim).
// R30 lesson: no kernel merges that break blockIdx->XCD shard alignment or
// mix LDS-heavy with LDS-light roles. R25: no edge-parallel LDS-atomic agg.
// Agg loop (R27 form): 2 nodes/wave, 4 octets x 8 lanes, stride 4, unroll
// 4; f32x2 packed accumulators (v_pk_add_f32); reduce shfl_xor(8,16).
// GEMM1 MFMA bf16 (R23): A row m = lane&15, B col n = lane&15, k-group =
// lane>>4, 8 consecutive k/lane; C/D col = lane&15, row = (lane>>4)*4 + reg.
// CSR build: LDS counting sort (R22), shard = blockIdx&3 (XCD-aligned).
// NOTE: __launch_bounds__(256,4) is 0-for-4 on this harness — do not use.
#define NN 100000
#define NE 1600000
#define NSHARD 4
#define SHARD_W (NN / NSHARD)   // 25000 exactly
#define NCHUNK 64
#define CHUNK_E (NE / NCHUNK)   // 25000 edges per chunk
#define CHUNK_I4 (CHUNK_E / 4)  // 6250 int4 per chunk

typedef __attribute__((ext_vector_type(8))) short bf16x8;
typedef __attribute__((ext_vector_type(4))) float f32x4;
typedef __attribute__((ext_vector_type(2))) float f32x2;

// bf16 helpers (manual, round-to-nearest-even; intermediates only)
__device__ inline unsigned f2bf(float f) {
    unsigned u = __float_as_uint(f);
    u += 0x7FFFu + ((u >> 16) & 1u);
    return u >> 16;
}
__device__ inline float bflo(unsigned v) { return __uint_as_float(v << 16); }
__device__ inline float bfhi(unsigned v) { return __uint_as_float(v & 0xFFFF0000u); }
// (lo, hi) pair for packed f32 accumulation (v_pk_add_f32)
__device__ inline f32x2 bfpair(unsigned u) {
    f32x2 r;
    r.x = __uint_as_float(u << 16);
    r.y = __uint_as_float(u & 0xFFFF0000u);
    return r;
}

// ---------------------------------------------------------------------------
// CSR build: LDS counting-sort (no device-scope atomics).
// ---------------------------------------------------------------------------
__global__ __launch_bounds__(256) void k_cnt(const int4* __restrict__ dst4,
                                             unsigned char* __restrict__ cnt,
                                             unsigned char* __restrict__ lrank) {
    __shared__ __align__(16) unsigned ldeg[SHARD_W];  // 100 KB (gfx950: 160 KB/CU)
    int t = threadIdx.x;
    int shard = blockIdx.x & (NSHARD - 1);
    int b = blockIdx.x >> 2;
    int lo = shard * SHARD_W;
    uint4 z4 = make_uint4(0u, 0u, 0u, 0u);
    for (int i = t; i < SHARD_W / 4; i += 256) ((uint4*)ldeg)[i] = z4;
    __syncthreads();
    const int4* p = dst4 + b * CHUNK_I4;
    unsigned char* lr = lrank + b * CHUNK_E;
#pragma unroll 4
    for (int j = t; j < CHUNK_I4; j += 256) {
        int4 d = p[j];
        unsigned ex = (unsigned)(d.x - lo);
        unsigned ey = (unsigned)(d.y - lo);
        unsigned ez = (unsigned)(d.z - lo);
        unsigned ew = (unsigned)(d.w - lo);
        if (ex < SHARD_W) lr[4 * j + 0] = (unsigned char)atomicAdd(&ldeg[ex], 1u);
        if (ey < SHARD_W) lr[4 * j + 1] = (unsigned char)atomicAdd(&ldeg[ey], 1u);
        if (ez < SHARD_W) lr[4 * j + 2] = (unsigned char)atomicAdd(&ldeg[ez], 1u);
        if (ew < SHARD_W) lr[4 * j + 3] = (unsigned char)atomicAdd(&ldeg[ew], 1u);
    }
    __syncthreads();
    unsigned* cb32 = (unsigned*)cnt + b * (NN / 4) + shard * (SHARD_W / 4);
    for (int i = t; i < SHARD_W / 4; i += 256) {
        uint4 v = *(const uint4*)&ldeg[4 * i];
        cb32[i] = (v.x & 255u) | ((v.y & 255u) << 8) | ((v.z & 255u) << 16)
                | ((v.w & 255u) << 24);
    }
}

// Pass B: per node (1 thread/node, byte ops), exclusive prefix across the
// 64 chunk counts (in place); total -> deg; block-sum -> bsums (fused bsum).
__global__ __launch_bounds__(256) void k_blkscan(unsigned char* __restrict__ cnt,
                                                 int* __restrict__ deg,
                                                 int* __restrict__ bsums) {
    __shared__ int s[256];
    int i = blockIdx.x * 256 + threadIdx.x;
    int total = 0;
    if (i < NN) {
        unsigned a = 0;
#pragma unroll
        for (int b = 0; b < NCHUNK; ++b) {
            unsigned v = cnt[b * NN + i];
            cnt[b * NN + i] = (unsigned char)a;
            a += v;
        }
        deg[i] = (int)a;
        total = (int)a;
    }
    s[threadIdx.x] = total;
    __syncthreads();
    for (int off = 128; off > 0; off >>= 1) {
        if (threadIdx.x < off) s[threadIdx.x] += s[threadIdx.x + off];
        __syncthreads();
    }
    if (threadIdx.x == 0) bsums[blockIdx.x] = s[0];
}

// rowptr + dis; global prefix base = masked reduce of bsums[j < blockIdx.x]
// (replicated per block -> k_scan512 launch eliminated).
__global__ void k_rowptr(const int* __restrict__ deg, const int* __restrict__ bsums,
                         int* __restrict__ rowptr, float* __restrict__ dis) {
    __shared__ int sbase[256];
    __shared__ int s[256];
    int t = threadIdx.x;
    int bid = blockIdx.x;
    int v = (t < bid) ? bsums[t] : 0;
    if (t + 256 < bid) v += bsums[t + 256];
    sbase[t] = v;
    __syncthreads();
    for (int off = 128; off > 0; off >>= 1) {
        if (t < off) sbase[t] += sbase[t + off];
        __syncthreads();
    }
    int base = sbase[0];
    int i = bid * 256 + t;
    int d = (i < NN) ? deg[i] : 0;
    s[t] = d;
    __syncthreads();
    for (int off = 1; off < 256; off <<= 1) {
        int x = (t >= off) ? s[t - off] : 0;
        __syncthreads();
        s[t] += x;
        __syncthreads();
    }
    if (i < NN) {
        rowptr[i] = base + s[t] - d;  // exclusive global prefix
        dis[i] = rsqrtf((float)(d + 1));  // +1 self-loop
    }
    if (i == 0) rowptr[NN] = NE;
}

// Atomic-free sharded scatter: pos = rowptr[dst] + blkoff[chunk][dst] + lrank.
// shard = blockIdx&3 MUST stay aligned with the block->XCD round-robin
// (R30 lesson: breaking it turns csr partial-line writes into HBM RMWs).
__global__ __launch_bounds__(256) void k_build_csr(
    const int4* __restrict__ src4, const int4* __restrict__ dst4,
    const unsigned char* __restrict__ blkoff, const unsigned* __restrict__ lr4,
    const int* __restrict__ rowptr, int* __restrict__ csr) {
    int shard = blockIdx.x & (NSHARD - 1);
    int bsh = blockIdx.x >> 2;
    int stride = (gridDim.x >> 2) * 256;
    int lo = shard * SHARD_W;
    const int NE4 = NE / 4;
    for (int i = bsh * 256 + threadIdx.x; i < NE4; i += stride) {
        int4 d = dst4[i];
        int4 s = src4[i];
        unsigned lr = lr4[i];
        const unsigned char* off = blkoff + (i / CHUNK_I4) * NN;
        unsigned ex = (unsigned)(d.x - lo);
        unsigned ey = (unsigned)(d.y - lo);
        unsigned ez = (unsigned)(d.z - lo);
        unsigned ew = (unsigned)(d.w - lo);
        if (ex < SHARD_W) csr[rowptr[d.x] + off[d.x] + (lr & 255u)] = s.x;
        if (ey < SHARD_W) csr[rowptr[d.y] + off[d.y] + ((lr >> 8) & 255u)] = s.y;
        if (ez < SHARD_W) csr[rowptr[d.z] + off[d.z] + ((lr >> 16) & 255u)] = s.z;
        if (ew < SHARD_W) csr[rowptr[d.w] + off[d.w] + (lr >> 24)] = s.w;
    }
}

// ---------------------------------------------------------------------------
// GEMM layer 1 (MFMA): tsb[row][c] = bf16( (x[row]@W1)[c] * dis[row] )
// ---------------------------------------------------------------------------
#define XS_LD 136  // 128 + 8 pad (bf16 units); stride%32words==4
__global__ __launch_bounds__(256) void k_gemm1(
    const float* __restrict__ x, const float* __restrict__ W,
    const float* __restrict__ dis, unsigned short* __restrict__ tsb) {
    __shared__ unsigned short xs[64 * XS_LD];
    __shared__ unsigned short wt[64 * XS_LD];
    int t = threadIdx.x;
    int row0 = blockIdx.x * 64;
    for (int i = t; i < 64 * 64; i += 256) {
        int n = i & 63, k2 = i >> 6;
        float w0 = W[(2 * k2) * 64 + n];
        float w1 = W[(2 * k2 + 1) * 64 + n];
        *(unsigned*)&wt[n * XS_LD + 2 * k2] = f2bf(w0) | (f2bf(w1) << 16);
    }
    for (int i = t; i < 64 * 32; i += 256) {
        int r = i >> 5, c4 = i & 31;
        int gr = row0 + r;
        uint2 p = {0u, 0u};
        if (gr < NN) {
            float4 v = *(const float4*)&x[gr * 128 + 4 * c4];
            p.x = f2bf(v.x) | (f2bf(v.y) << 16);
            p.y = f2bf(v.z) | (f2bf(v.w) << 16);
        }
        *(uint2*)&xs[r * XS_LD + 4 * c4] = p;
    }
    __syncthreads();
    int w = t >> 6, l = t & 63;
    int lm = l & 15, lg = l >> 4;
    const unsigned short* ap = &xs[(16 * w + lm) * XS_LD + 8 * lg];
    const unsigned short* bp = &wt[lm * XS_LD + 8 * lg];
    f32x4 acc0 = {0, 0, 0, 0}, acc1 = {0, 0, 0, 0}, acc2 = {0, 0, 0, 0}, acc3 = {0, 0, 0, 0};
#pragma unroll
    for (int kb = 0; kb < 4; ++kb) {
        bf16x8 a  = *(const bf16x8*)(ap + 32 * kb);
        bf16x8 b0 = *(const bf16x8*)(bp + 32 * kb);
        bf16x8 b1 = *(const bf16x8*)(bp + 16 * XS_LD + 32 * kb);
        bf16x8 b2 = *(const bf16x8*)(bp + 32 * XS_LD + 32 * kb);
        bf16x8 b3 = *(const bf16x8*)(bp + 48 * XS_LD + 32 * kb);
        acc0 = __builtin_amdgcn_mfma_f32_16x16x32_bf16(a, b0, acc0, 0, 0, 0);
        acc1 = __builtin_amdgcn_mfma_f32_16x16x32_bf16(a, b1, acc1, 0, 0, 0);
        acc2 = __builtin_amdgcn_mfma_f32_16x16x32_bf16(a, b2, acc2, 0, 0, 0);
        acc3 = __builtin_amdgcn_mfma_f32_16x16x32_bf16(a, b3, acc3, 0, 0, 0);
    }
    int rbase = row0 + 16 * w + 4 * lg;
#pragma unroll
    for (int r = 0; r < 4; ++r) {
        int row = rbase + r;
        if (row < NN) {
            float dv = dis[row];
            unsigned short* o = &tsb[row * 64 + lm];
            o[0]  = (unsigned short)f2bf(acc0[r] * dv);
            o[16] = (unsigned short)f2bf(acc1[r] * dv);
            o[32] = (unsigned short)f2bf(acc2[r] * dv);
            o[48] = (unsigned short)f2bf(acc3[r] * dv);
        }
    }
}

// ---------------------------------------------------------------------------
// Fused aggregation + dis scale + bias + ReLU (R27 gather loop, verbatim).
// TWO nodes per wave (32-lane half each), grid-stride. Per half: 4 octets x
// 8 lanes; octet walks edges at stride 4, unroll 4 -> 16 rows in flight per
// half, 32 per wave. f32x2 packed accumulators; reduce = shfl_xor(8,16).
// Epilogue variants (epilogue-only edits are schedule-safe, R29 lesson):
//  MODE==1 (FUSE2): ts2[node][c] = (relu_h @ W2)[c] * dis  -> outb (bf16).
//    W2 staged f32 in LDS (16KB); per node: 64x{shfl h_k, 2 ds_read_b128,
//    8 FMA} across the 8 oct0 lanes. Replaces k_gemm2 entirely.
//  MODE==2 (FUSE3): t3[node] = dot(relu_h, W3)*dis (scalar out, R29 form).
// ---------------------------------------------------------------------------
#define AGG_BLOCKS 2048
template <int MODE>
__global__ __launch_bounds__(256) void k_agg_relu(
    const unsigned short* __restrict__ tsb, const int* __restrict__ rowptr,
    const int* __restrict__ csr, const float* __restrict__ dis,
    const float* __restrict__ b, const float* __restrict__ Wx,
    unsigned short* __restrict__ outb, float* __restrict__ t3) {
    __shared__ float Ws[(MODE == 1) ? 64 * 64 : 1];
    if (MODE == 1) {
        for (int i = threadIdx.x; i < 64 * 64; i += 256) Ws[i] = Wx[i];
        __syncthreads();
    }
    int wid = blockIdx.x * 4 + (threadIdx.x >> 6);
    const int nwaves = AGG_BLOCKS * 4;  // 8192
    int lane = threadIdx.x & 63;
    int half = lane >> 5;        // node select within wave
    int oct = (lane >> 3) & 3;   // octet 0..3 within half
    int fl = lane & 7;           // feature octet: features 8*fl .. 8*fl+7
    const uint4* ts128 = (const uint4*)tsb;  // row stride 8 uint4
    for (int base = wid * 2; base < NN; base += nwaves * 2) {
        int node = base + half;
        bool valid = node < NN;
        f32x2 a0 = {0.f, 0.f}, a1 = {0.f, 0.f}, a2 = {0.f, 0.f}, a3 = {0.f, 0.f};
        if (valid) {
            if (oct == 0) {  // self-loop term, added once
                uint4 v = ts128[node * 8 + fl];
                a0 += bfpair(v.x); a1 += bfpair(v.y); a2 += bfpair(v.z); a3 += bfpair(v.w);
            }
            int e = rowptr[node] + oct, end = rowptr[node + 1];
            // per-octet stride 4; unroll 4 -> 16 rows in flight per half
            for (; e + 12 < end; e += 16) {
                int s0 = csr[e];
                int s1 = csr[e + 4];
                int s2 = csr[e + 8];
                int s3 = csr[e + 12];
                uint4 v0 = ts128[s0 * 8 + fl];
                uint4 v1 = ts128[s1 * 8 + fl];
                uint4 v2 = ts128[s2 * 8 + fl];
                uint4 v3 = ts128[s3 * 8 + fl];
                a0 += bfpair(v0.x); a1 += bfpair(v0.y); a2 += bfpair(v0.z); a3 += bfpair(v0.w);
                a0 += bfpair(v1.x); a1 += bfpair(v1.y); a2 += bfpair(v1.z); a3 += bfpair(v1.w);
                a0 += bfpair(v2.x); a1 += bfpair(v2.y); a2 += bfpair(v2.z); a3 += bfpair(v2.w);
                a0 += bfpair(v3.x); a1 += bfpair(v3.y); a2 += bfpair(v3.z); a3 += bfpair(v3.w);
            }
            for (; e < end; e += 4) {
                uint4 v = ts128[csr[e] * 8 + fl];
                a0 += bfpair(v.x); a1 += bfpair(v.y); a2 += bfpair(v.z); a3 += bfpair(v.w);
            }
        }
        // combine octets within each 32-lane half (xor 8, 16 stay in half)
#pragma unroll
        for (int off = 8; off <= 16; off <<= 1) {
            a0.x += __shfl_xor(a0.x, off); a0.y += __shfl_xor(a0.y, off);
            a1.x += __shfl_xor(a1.x, off); a1.y += __shfl_xor(a1.y, off);
            a2.x += __shfl_xor(a2.x, off); a2.y += __shfl_xor(a2.y, off);
            a3.x += __shfl_xor(a3.x, off); a3.y += __shfl_xor(a3.y, off);
        }
        if (oct == 0) {
            float dv = valid ? dis[node] : 0.f;
            float v0 = fmaxf(a0.x * dv + b[8 * fl + 0], 0.f);
            float v1 = fmaxf(a0.y * dv + b[8 * fl + 1], 0.f);
            float v2 = fmaxf(a1.x * dv + b[8 * fl + 2], 0.f);
            float v3 = fmaxf(a1.y * dv + b[8 * fl + 3], 0.f);
            float v4 = fmaxf(a2.x * dv + b[8 * fl + 4], 0.f);
            float v5 = fmaxf(a2.y * dv + b[8 * fl + 5], 0.f);
            float v6 = fmaxf(a3.x * dv + b[8 * fl + 6], 0.f);
            float v7 = fmaxf(a3.y * dv + b[8 * fl + 7], 0.f);
            if (MODE == 1) {
                // layer-2 GEMM fused: ts2[c] = (h @ W2)[c] * dis, c in
                // {8fl..8fl+7}. h[k]=h[8*kf+kr] lives as v_kr of lane kf;
                // broadcast via shfl within this half's oct0 lanes (all
                // active here; invalid half contributes only to itself).
                float hv[8] = {v0, v1, v2, v3, v4, v5, v6, v7};
                float c0 = 0.f, c1 = 0.f, c2 = 0.f, c3 = 0.f;
                float c4 = 0.f, c5 = 0.f, c6 = 0.f, c7 = 0.f;
                int sbase = half << 5;
#pragma unroll
                for (int kr = 0; kr < 8; ++kr) {
                    float hs = hv[kr];
#pragma unroll
                    for (int kf = 0; kf < 8; ++kf) {
                        float hk = __shfl(hs, sbase + kf, 64);
                        const float* wr = &Ws[(kf * 8 + kr) * 64 + 8 * fl];
                        float4 wa = *(const float4*)wr;
                        float4 wb = *(const float4*)(wr + 4);
                        c0 += hk * wa.x; c1 += hk * wa.y;
                        c2 += hk * wa.z; c3 += hk * wa.w;
                        c4 += hk * wb.x; c5 += hk * wb.y;
                        c6 += hk * wb.z; c7 += hk * wb.w;
                    }
                }
                if (valid) {
                    uint4 p;
                    p.x = f2bf(c0 * dv) | (f2bf(c1 * dv) << 16);
                    p.y = f2bf(c2 * dv) | (f2bf(c3 * dv) << 16);
                    p.z = f2bf(c4 * dv) | (f2bf(c5 * dv) << 16);
                    p.w = f2bf(c6 * dv) | (f2bf(c7 * dv) << 16);
                    ((uint4*)outb)[node * 8 + fl] = p;
                }
            } else if (MODE == 2) {
                // layer-3 projection fused: t3 = dot(h, W3) * dis
                float part = v0 * Wx[8 * fl + 0] + v1 * Wx[8 * fl + 1]
                           + v2 * Wx[8 * fl + 2] + v3 * Wx[8 * fl + 3]
                           + v4 * Wx[8 * fl + 4] + v5 * Wx[8 * fl + 5]
                           + v6 * Wx[8 * fl + 6] + v7 * Wx[8 * fl + 7];
                part += __shfl_xor(part, 1);
                part += __shfl_xor(part, 2);
                part += __shfl_xor(part, 4);
                if (valid && fl == 0) t3[node] = part * dv;
            } else if (valid) {
                uint4 p;
                p.x = f2bf(v0) | (f2bf(v1) << 16);
                p.y = f2bf(v2) | (f2bf(v3) << 16);
                p.z = f2bf(v4) | (f2bf(v5) << 16);
                p.w = f2bf(v6) | (f2bf(v7) << 16);
                ((uint4*)outb)[node * 8 + fl] = p;
            }
        }
    }
}

// ---------------------------------------------------------------------------
// Fused layer-3 aggregation + sigmoid. Wave = 8 nodes x 8 lanes; per-lane
// edge stride 8, unroll 2; shfl_xor(1,2,4) reduce within the 8-lane group.
// ---------------------------------------------------------------------------
__global__ void k_out(const float* __restrict__ t3, const int* __restrict__ rowptr,
                      const int* __restrict__ csr, const float* __restrict__ dis,
                      const float* __restrict__ b3, float* __restrict__ out) {
    int wv = blockIdx.x * 4 + (threadIdx.x >> 6);
    int lane = threadIdx.x & 63;
    int g = lane >> 3;   // node group 0..7 within wave
    int sl = lane & 7;   // sub-lane within group
    int node = wv * 8 + g;
    if (node >= NN) return;  // no barriers below: divergent return safe
    float acc = (sl == 0) ? t3[node] : 0.f;  // self-loop term
    float acc1 = 0.f;
    int e = rowptr[node] + sl, end = rowptr[node + 1];
    for (; e + 8 < end; e += 16) {
        acc += t3[csr[e]];
        acc1 += t3[csr[e + 8]];
    }
    if (e < end) acc += t3[csr[e]];
    acc += acc1;
    acc += __shfl_xor(acc, 1);
    acc += __shfl_xor(acc, 2);
    acc += __shfl_xor(acc, 4);
    if (sl == 0) {
        float z = acc * dis[node] + b3[0];
        out[node] = 1.f / (1.f + __expf(-z));
    }
}

// ---------------------------------------------------------------------------
extern "C" void kernel_launch(void* const* d_in, const int* in_sizes, int n_in,
                              void* d_out, int out_size, void* d_ws, size_t ws_size,
                              hipStream_t stream) {
    const float* x  = (const float*)d_in[0];   // N x 128
    const float* W1 = (const float*)d_in[1];   // 128 x 64
    const float* b1 = (const float*)d_in[2];   // 64
    const float* W2 = (const float*)d_in[3];   // 64 x 64
    const float* b2 = (const float*)d_in[4];   // 64
    const float* W3 = (const float*)d_in[5];   // 64 x 1
    const float* b3 = (const float*)d_in[6];   // 1
    const int*   ei = (const int*)d_in[7];     // 2 x E
    const int* src = ei;
    const int* dst = ei + NE;
    float* out = (float*)d_out;

    // Workspace layout
    unsigned short* TSB = (unsigned short*)d_ws;          // N*64 bf16 (ts1)
    unsigned short* HB  = TSB + (size_t)NN * 64;          // N*64 bf16 (ts2)
    float* dis    = (float*)(HB + (size_t)NN * 64);       // N
    float* t3     = dis + NN;                             // N
    int*   deg    = (int*)(t3 + NN);                      // N
    int*   rowptr = deg + NN;                             // N+1 (+pad)
    int*   bsums  = rowptr + NN + 8;                      // 512
    int*   csr    = bsums + 512;                          // E
    // Aliased scratch (dead before the aliasee is first written):
    unsigned char* lrank = (unsigned char*)TSB;  // E bytes; dead before k_gemm1
    unsigned char* cnt   = (unsigned char*)HB;   // NCHUNK*NN bytes; dead before agg1 writes HB

    const int nbN = (NN + 255) / 256;       // 391
    const int nbG = (NN + 63) / 64;         // 1563
    const int nbOut = (NN + 31) / 32;       // 3125

    // CSR build + normalization (LDS counting sort, no device-scope atomics)
    k_cnt<<<NSHARD * NCHUNK, 256, 0, stream>>>((const int4*)dst, cnt, lrank);
    k_blkscan<<<nbN, 256, 0, stream>>>(cnt, deg, bsums);
    k_rowptr<<<nbN, 256, 0, stream>>>(deg, bsums, rowptr, dis);
    k_build_csr<<<2048, 256, 0, stream>>>((const int4*)src, (const int4*)dst,
                                          cnt, (const unsigned*)lrank, rowptr, csr);

    // Layer 1 GEMM
    k_gemm1<<<nbG, 256, 0, stream>>>(x, W1, dis, TSB);

    // Layer 1 aggregation + fused layer-2 GEMM (ts1 -> ts2 in HB)
    k_agg_relu<1><<<AGG_BLOCKS, 256, 0, stream>>>(TSB, rowptr, csr, dis, b1, W2, HB, t3);

    // Layer 2 aggregation + fused layer-3 projection (ts2 -> t3)
    k_agg_relu<2><<<AGG_BLOCKS, 256, 0, stream>>>(HB, rowptr, csr, dis, b2, W3, TSB, t3);

    // Layer 3 output
    k_out<<<nbOut, 256, 0, stream>>>(t3, rowptr, csr, dis, b3, out);
}

// Round 12
// 264.028 us; speedup vs baseline: 1.9549x; 1.9549x over previous
//
#include <hip/hip_runtime.h>
#include <math.h>

// N=100000 nodes, E=1600000 edges, features 128 -> 64 -> 64 -> 1.
// R33 = R31 restored VERBATIM (champion, 264.5us).
// R32 post-mortem (FUSE2: W2 matmul in agg1 epilogue, REVERTED): agg1 ran
// 313us @ VGPR 160, occupancy 11% (was 24 / ~70%). The 64-iter shfl+FMA
// epilogue blew registers for the WHOLE kernel; the latency-bound gather
// loop lives on wave parallelism and collapsed. LESSON (revises R29):
// "epilogue-only" is NOT the safety criterion — "preserves VGPR class /
// occupancy" is. Register pressure is kernel-global; a big epilogue taxes
// every wave all the time. FUSE3 (8 FMA + 3 shfl) is fine; FUSE2 is not.
// Failed-structure ledger (do not retry):
//  R25 edge-parallel LDS-atomic agg: 48->71us (divergent flush, ds atomics)
//  R28 agg loop prefetch/reg-hoists: +13us/dispatch (broke gather schedule)
//  R30 csr+gemm1 merge: 74-80us (broke shard&3<->XCD align; LDS tax on
//      scatter blocks). Shard writes need blockIdx&3 alignment.
//  R32 FUSE2 W2-in-epilogue: VGPR 160, occ 11%, 313us.
// Surviving structure:
//  CSR: LDS counting sort (k_cnt 4sh x 64chunks) -> blkscan(+bsum fused)
//       -> rowptr(+scan fused) -> build_csr (shard=blockIdx&3, XCD-aligned)
//  L1:  gemm1 (MFMA bf16) -> agg<0> (R27 gather loop: 2 nodes/wave,
//       4 oct x 8 lanes, stride 4, unroll 4, f32x2 pk-acc, shfl_xor(8,16))
//  L2:  gemm2 (MFMA, W2 hi+lo bf16 split) -> agg<FUSE3> (t3 = dot(h,W3)*dis)
//  L3:  k_out (8 lanes/node, shfl_xor(1,2,4))
// GEMM fragments (R23): A row m = lane&15, B col n = lane&15, k-group =
// lane>>4, 8 consecutive k/lane; C/D col = lane&15, row = (lane>>4)*4 + reg.
// NOTE: __launch_bounds__(256,4) is 0-for-4 on this harness — do not use.
#define NN 100000
#define NE 1600000
#define NSHARD 4
#define SHARD_W (NN / NSHARD)   // 25000 exactly
#define NCHUNK 64
#define CHUNK_E (NE / NCHUNK)   // 25000 edges per chunk
#define CHUNK_I4 (CHUNK_E / 4)  // 6250 int4 per chunk

typedef __attribute__((ext_vector_type(8))) short bf16x8;
typedef __attribute__((ext_vector_type(4))) float f32x4;
typedef __attribute__((ext_vector_type(2))) float f32x2;

// bf16 helpers (manual, round-to-nearest-even; intermediates only)
__device__ inline unsigned f2bf(float f) {
    unsigned u = __float_as_uint(f);
    u += 0x7FFFu + ((u >> 16) & 1u);
    return u >> 16;
}
__device__ inline float bflo(unsigned v) { return __uint_as_float(v << 16); }
__device__ inline float bfhi(unsigned v) { return __uint_as_float(v & 0xFFFF0000u); }
// (lo, hi) pair for packed f32 accumulation (v_pk_add_f32)
__device__ inline f32x2 bfpair(unsigned u) {
    f32x2 r;
    r.x = __uint_as_float(u << 16);
    r.y = __uint_as_float(u & 0xFFFF0000u);
    return r;
}

// ---------------------------------------------------------------------------
// CSR build: LDS counting-sort (no device-scope atomics).
// ---------------------------------------------------------------------------
__global__ __launch_bounds__(256) void k_cnt(const int4* __restrict__ dst4,
                                             unsigned char* __restrict__ cnt,
                                             unsigned char* __restrict__ lrank) {
    __shared__ __align__(16) unsigned ldeg[SHARD_W];  // 100 KB (gfx950: 160 KB/CU)
    int t = threadIdx.x;
    int shard = blockIdx.x & (NSHARD - 1);
    int b = blockIdx.x >> 2;
    int lo = shard * SHARD_W;
    uint4 z4 = make_uint4(0u, 0u, 0u, 0u);
    for (int i = t; i < SHARD_W / 4; i += 256) ((uint4*)ldeg)[i] = z4;
    __syncthreads();
    const int4* p = dst4 + b * CHUNK_I4;
    unsigned char* lr = lrank + b * CHUNK_E;
#pragma unroll 4
    for (int j = t; j < CHUNK_I4; j += 256) {
        int4 d = p[j];
        unsigned ex = (unsigned)(d.x - lo);
        unsigned ey = (unsigned)(d.y - lo);
        unsigned ez = (unsigned)(d.z - lo);
        unsigned ew = (unsigned)(d.w - lo);
        if (ex < SHARD_W) lr[4 * j + 0] = (unsigned char)atomicAdd(&ldeg[ex], 1u);
        if (ey < SHARD_W) lr[4 * j + 1] = (unsigned char)atomicAdd(&ldeg[ey], 1u);
        if (ez < SHARD_W) lr[4 * j + 2] = (unsigned char)atomicAdd(&ldeg[ez], 1u);
        if (ew < SHARD_W) lr[4 * j + 3] = (unsigned char)atomicAdd(&ldeg[ew], 1u);
    }
    __syncthreads();
    unsigned* cb32 = (unsigned*)cnt + b * (NN / 4) + shard * (SHARD_W / 4);
    for (int i = t; i < SHARD_W / 4; i += 256) {
        uint4 v = *(const uint4*)&ldeg[4 * i];
        cb32[i] = (v.x & 255u) | ((v.y & 255u) << 8) | ((v.z & 255u) << 16)
                | ((v.w & 255u) << 24);
    }
}

// Pass B: per node (1 thread/node, byte ops), exclusive prefix across the
// 64 chunk counts (in place); total -> deg; block-sum -> bsums (fused bsum).
__global__ __launch_bounds__(256) void k_blkscan(unsigned char* __restrict__ cnt,
                                                 int* __restrict__ deg,
                                                 int* __restrict__ bsums) {
    __shared__ int s[256];
    int i = blockIdx.x * 256 + threadIdx.x;
    int total = 0;
    if (i < NN) {
        unsigned a = 0;
#pragma unroll
        for (int b = 0; b < NCHUNK; ++b) {
            unsigned v = cnt[b * NN + i];
            cnt[b * NN + i] = (unsigned char)a;
            a += v;
        }
        deg[i] = (int)a;
        total = (int)a;
    }
    s[threadIdx.x] = total;
    __syncthreads();
    for (int off = 128; off > 0; off >>= 1) {
        if (threadIdx.x < off) s[threadIdx.x] += s[threadIdx.x + off];
        __syncthreads();
    }
    if (threadIdx.x == 0) bsums[blockIdx.x] = s[0];
}

// rowptr + dis; global prefix base = masked reduce of bsums[j < blockIdx.x]
// (replicated per block -> k_scan512 launch eliminated).
__global__ void k_rowptr(const int* __restrict__ deg, const int* __restrict__ bsums,
                         int* __restrict__ rowptr, float* __restrict__ dis) {
    __shared__ int sbase[256];
    __shared__ int s[256];
    int t = threadIdx.x;
    int bid = blockIdx.x;
    int v = (t < bid) ? bsums[t] : 0;
    if (t + 256 < bid) v += bsums[t + 256];
    sbase[t] = v;
    __syncthreads();
    for (int off = 128; off > 0; off >>= 1) {
        if (t < off) sbase[t] += sbase[t + off];
        __syncthreads();
    }
    int base = sbase[0];
    int i = bid * 256 + t;
    int d = (i < NN) ? deg[i] : 0;
    s[t] = d;
    __syncthreads();
    for (int off = 1; off < 256; off <<= 1) {
        int x = (t >= off) ? s[t - off] : 0;
        __syncthreads();
        s[t] += x;
        __syncthreads();
    }
    if (i < NN) {
        rowptr[i] = base + s[t] - d;  // exclusive global prefix
        dis[i] = rsqrtf((float)(d + 1));  // +1 self-loop
    }
    if (i == 0) rowptr[NN] = NE;
}

// Atomic-free sharded scatter: pos = rowptr[dst] + blkoff[chunk][dst] + lrank.
// shard = blockIdx&3 MUST stay aligned with the block->XCD round-robin
// (R30 lesson: breaking it turns csr partial-line writes into HBM RMWs).
__global__ __launch_bounds__(256) void k_build_csr(
    const int4* __restrict__ src4, const int4* __restrict__ dst4,
    const unsigned char* __restrict__ blkoff, const unsigned* __restrict__ lr4,
    const int* __restrict__ rowptr, int* __restrict__ csr) {
    int shard = blockIdx.x & (NSHARD - 1);
    int bsh = blockIdx.x >> 2;
    int stride = (gridDim.x >> 2) * 256;
    int lo = shard * SHARD_W;
    const int NE4 = NE / 4;
    for (int i = bsh * 256 + threadIdx.x; i < NE4; i += stride) {
        int4 d = dst4[i];
        int4 s = src4[i];
        unsigned lr = lr4[i];
        const unsigned char* off = blkoff + (i / CHUNK_I4) * NN;
        unsigned ex = (unsigned)(d.x - lo);
        unsigned ey = (unsigned)(d.y - lo);
        unsigned ez = (unsigned)(d.z - lo);
        unsigned ew = (unsigned)(d.w - lo);
        if (ex < SHARD_W) csr[rowptr[d.x] + off[d.x] + (lr & 255u)] = s.x;
        if (ey < SHARD_W) csr[rowptr[d.y] + off[d.y] + ((lr >> 8) & 255u)] = s.y;
        if (ez < SHARD_W) csr[rowptr[d.z] + off[d.z] + ((lr >> 16) & 255u)] = s.z;
        if (ew < SHARD_W) csr[rowptr[d.w] + off[d.w] + (lr >> 24)] = s.w;
    }
}

// ---------------------------------------------------------------------------
// GEMM layer 1 (MFMA): tsb[row][c] = bf16( (x[row]@W1)[c] * dis[row] )
// ---------------------------------------------------------------------------
#define XS_LD 136  // 128 + 8 pad (bf16 units); stride%32words==4
__global__ __launch_bounds__(256) void k_gemm1(
    const float* __restrict__ x, const float* __restrict__ W,
    const float* __restrict__ dis, unsigned short* __restrict__ tsb) {
    __shared__ unsigned short xs[64 * XS_LD];
    __shared__ unsigned short wt[64 * XS_LD];
    int t = threadIdx.x;
    int row0 = blockIdx.x * 64;
    for (int i = t; i < 64 * 64; i += 256) {
        int n = i & 63, k2 = i >> 6;
        float w0 = W[(2 * k2) * 64 + n];
        float w1 = W[(2 * k2 + 1) * 64 + n];
        *(unsigned*)&wt[n * XS_LD + 2 * k2] = f2bf(w0) | (f2bf(w1) << 16);
    }
    for (int i = t; i < 64 * 32; i += 256) {
        int r = i >> 5, c4 = i & 31;
        int gr = row0 + r;
        uint2 p = {0u, 0u};
        if (gr < NN) {
            float4 v = *(const float4*)&x[gr * 128 + 4 * c4];
            p.x = f2bf(v.x) | (f2bf(v.y) << 16);
            p.y = f2bf(v.z) | (f2bf(v.w) << 16);
        }
        *(uint2*)&xs[r * XS_LD + 4 * c4] = p;
    }
    __syncthreads();
    int w = t >> 6, l = t & 63;
    int lm = l & 15, lg = l >> 4;
    const unsigned short* ap = &xs[(16 * w + lm) * XS_LD + 8 * lg];
    const unsigned short* bp = &wt[lm * XS_LD + 8 * lg];
    f32x4 acc0 = {0, 0, 0, 0}, acc1 = {0, 0, 0, 0}, acc2 = {0, 0, 0, 0}, acc3 = {0, 0, 0, 0};
#pragma unroll
    for (int kb = 0; kb < 4; ++kb) {
        bf16x8 a  = *(const bf16x8*)(ap + 32 * kb);
        bf16x8 b0 = *(const bf16x8*)(bp + 32 * kb);
        bf16x8 b1 = *(const bf16x8*)(bp + 16 * XS_LD + 32 * kb);
        bf16x8 b2 = *(const bf16x8*)(bp + 32 * XS_LD + 32 * kb);
        bf16x8 b3 = *(const bf16x8*)(bp + 48 * XS_LD + 32 * kb);
        acc0 = __builtin_amdgcn_mfma_f32_16x16x32_bf16(a, b0, acc0, 0, 0, 0);
        acc1 = __builtin_amdgcn_mfma_f32_16x16x32_bf16(a, b1, acc1, 0, 0, 0);
        acc2 = __builtin_amdgcn_mfma_f32_16x16x32_bf16(a, b2, acc2, 0, 0, 0);
        acc3 = __builtin_amdgcn_mfma_f32_16x16x32_bf16(a, b3, acc3, 0, 0, 0);
    }
    int rbase = row0 + 16 * w + 4 * lg;
#pragma unroll
    for (int r = 0; r < 4; ++r) {
        int row = rbase + r;
        if (row < NN) {
            float dv = dis[row];
            unsigned short* o = &tsb[row * 64 + lm];
            o[0]  = (unsigned short)f2bf(acc0[r] * dv);
            o[16] = (unsigned short)f2bf(acc1[r] * dv);
            o[32] = (unsigned short)f2bf(acc2[r] * dv);
            o[48] = (unsigned short)f2bf(acc3[r] * dv);
        }
    }
}

// ---------------------------------------------------------------------------
// GEMM layer 2 (MFMA): K=64, h is bf16 already. W2 split hi+lo bf16.
// ---------------------------------------------------------------------------
#define HS_LD 72  // 64 + 8 pad (bf16 units); stride%32words==4
__global__ __launch_bounds__(256) void k_gemm2(
    const unsigned short* __restrict__ hb, const float* __restrict__ W,
    const float* __restrict__ dis, unsigned short* __restrict__ tsb) {
    __shared__ unsigned short hs[64 * HS_LD];
    __shared__ unsigned short wh[64 * HS_LD];
    __shared__ unsigned short wl[64 * HS_LD];
    int t = threadIdx.x;
    int row0 = blockIdx.x * 64;
    for (int i = t; i < 64 * 32; i += 256) {
        int n = i & 63, k2 = i >> 6;
        float w0 = W[(2 * k2) * 64 + n];
        float w1 = W[(2 * k2 + 1) * 64 + n];
        unsigned h0 = f2bf(w0), h1 = f2bf(w1);
        *(unsigned*)&wh[n * HS_LD + 2 * k2] = h0 | (h1 << 16);
        float r0 = w0 - bflo(h0), r1 = w1 - bflo(h1);
        *(unsigned*)&wl[n * HS_LD + 2 * k2] = f2bf(r0) | (f2bf(r1) << 16);
    }
    const uint4* h4 = (const uint4*)hb;
    for (int i = t; i < 64 * 8; i += 256) {
        int r = i >> 3, c8 = i & 7;
        int gr = row0 + r;
        uint4 v = (gr < NN) ? h4[gr * 8 + c8] : make_uint4(0u, 0u, 0u, 0u);
        *(uint4*)&hs[r * HS_LD + 8 * c8] = v;
    }
    __syncthreads();
    int w = t >> 6, l = t & 63;
    int lm = l & 15, lg = l >> 4;
    const unsigned short* ap = &hs[(16 * w + lm) * HS_LD + 8 * lg];
    const unsigned short* bh = &wh[lm * HS_LD + 8 * lg];
    const unsigned short* bl = &wl[lm * HS_LD + 8 * lg];
    f32x4 acc0 = {0, 0, 0, 0}, acc1 = {0, 0, 0, 0}, acc2 = {0, 0, 0, 0}, acc3 = {0, 0, 0, 0};
#pragma unroll
    for (int kb = 0; kb < 2; ++kb) {
        bf16x8 a  = *(const bf16x8*)(ap + 32 * kb);
        bf16x8 h0 = *(const bf16x8*)(bh + 32 * kb);
        bf16x8 h1 = *(const bf16x8*)(bh + 16 * HS_LD + 32 * kb);
        bf16x8 h2 = *(const bf16x8*)(bh + 32 * HS_LD + 32 * kb);
        bf16x8 h3 = *(const bf16x8*)(bh + 48 * HS_LD + 32 * kb);
        bf16x8 l0 = *(const bf16x8*)(bl + 32 * kb);
        bf16x8 l1 = *(const bf16x8*)(bl + 16 * HS_LD + 32 * kb);
        bf16x8 l2 = *(const bf16x8*)(bl + 32 * HS_LD + 32 * kb);
        bf16x8 l3 = *(const bf16x8*)(bl + 48 * HS_LD + 32 * kb);
        acc0 = __builtin_amdgcn_mfma_f32_16x16x32_bf16(a, h0, acc0, 0, 0, 0);
        acc1 = __builtin_amdgcn_mfma_f32_16x16x32_bf16(a, h1, acc1, 0, 0, 0);
        acc2 = __builtin_amdgcn_mfma_f32_16x16x32_bf16(a, h2, acc2, 0, 0, 0);
        acc3 = __builtin_amdgcn_mfma_f32_16x16x32_bf16(a, h3, acc3, 0, 0, 0);
        acc0 = __builtin_amdgcn_mfma_f32_16x16x32_bf16(a, l0, acc0, 0, 0, 0);
        acc1 = __builtin_amdgcn_mfma_f32_16x16x32_bf16(a, l1, acc1, 0, 0, 0);
        acc2 = __builtin_amdgcn_mfma_f32_16x16x32_bf16(a, l2, acc2, 0, 0, 0);
        acc3 = __builtin_amdgcn_mfma_f32_16x16x32_bf16(a, l3, acc3, 0, 0, 0);
    }
    int rbase = row0 + 16 * w + 4 * lg;
#pragma unroll
    for (int r = 0; r < 4; ++r) {
        int row = rbase + r;
        if (row < NN) {
            float dv = dis[row];
            unsigned short* o = &tsb[row * 64 + lm];
            o[0]  = (unsigned short)f2bf(acc0[r] * dv);
            o[16] = (unsigned short)f2bf(acc1[r] * dv);
            o[32] = (unsigned short)f2bf(acc2[r] * dv);
            o[48] = (unsigned short)f2bf(acc3[r] * dv);
        }
    }
}

// ---------------------------------------------------------------------------
// Fused aggregation + dis scale + bias + ReLU (R27 body, verbatim loop).
// TWO nodes per wave (32-lane half each), grid-stride. Per half: 4 octets x
// 8 lanes; octet walks edges at stride 4, unroll 4 -> 16 rows in flight per
// half, 32 per wave. f32x2 packed accumulators; reduce = shfl_xor(8,16).
// FUSE3 (small epilogue substitution): t3[node] = dot(relu_h, W3)*dis.
// VGPR 24 — keep it that way (R32 lesson: occupancy is the fragility axis).
// ---------------------------------------------------------------------------
#define AGG_BLOCKS 2048
template <bool FUSE3>
__global__ __launch_bounds__(256) void k_agg_relu(
    const unsigned short* __restrict__ tsb, const int* __restrict__ rowptr,
    const int* __restrict__ csr, const float* __restrict__ dis,
    const float* __restrict__ b, const float* __restrict__ W3,
    unsigned short* __restrict__ hb, float* __restrict__ t3) {
    int wid = blockIdx.x * 4 + (threadIdx.x >> 6);
    const int nwaves = AGG_BLOCKS * 4;  // 8192
    int lane = threadIdx.x & 63;
    int half = lane >> 5;        // node select within wave
    int oct = (lane >> 3) & 3;   // octet 0..3 within half
    int fl = lane & 7;           // feature octet: features 8*fl .. 8*fl+7
    const uint4* ts128 = (const uint4*)tsb;  // row stride 8 uint4
    for (int base = wid * 2; base < NN; base += nwaves * 2) {
        int node = base + half;
        bool valid = node < NN;
        f32x2 a0 = {0.f, 0.f}, a1 = {0.f, 0.f}, a2 = {0.f, 0.f}, a3 = {0.f, 0.f};
        if (valid) {
            if (oct == 0) {  // self-loop term, added once
                uint4 v = ts128[node * 8 + fl];
                a0 += bfpair(v.x); a1 += bfpair(v.y); a2 += bfpair(v.z); a3 += bfpair(v.w);
            }
            int e = rowptr[node] + oct, end = rowptr[node + 1];
            // per-octet stride 4; unroll 4 -> 16 rows in flight per half
            for (; e + 12 < end; e += 16) {
                int s0 = csr[e];
                int s1 = csr[e + 4];
                int s2 = csr[e + 8];
                int s3 = csr[e + 12];
                uint4 v0 = ts128[s0 * 8 + fl];
                uint4 v1 = ts128[s1 * 8 + fl];
                uint4 v2 = ts128[s2 * 8 + fl];
                uint4 v3 = ts128[s3 * 8 + fl];
                a0 += bfpair(v0.x); a1 += bfpair(v0.y); a2 += bfpair(v0.z); a3 += bfpair(v0.w);
                a0 += bfpair(v1.x); a1 += bfpair(v1.y); a2 += bfpair(v1.z); a3 += bfpair(v1.w);
                a0 += bfpair(v2.x); a1 += bfpair(v2.y); a2 += bfpair(v2.z); a3 += bfpair(v2.w);
                a0 += bfpair(v3.x); a1 += bfpair(v3.y); a2 += bfpair(v3.z); a3 += bfpair(v3.w);
            }
            for (; e < end; e += 4) {
                uint4 v = ts128[csr[e] * 8 + fl];
                a0 += bfpair(v.x); a1 += bfpair(v.y); a2 += bfpair(v.z); a3 += bfpair(v.w);
            }
        }
        // combine octets within each 32-lane half (xor 8, 16 stay in half)
#pragma unroll
        for (int off = 8; off <= 16; off <<= 1) {
            a0.x += __shfl_xor(a0.x, off); a0.y += __shfl_xor(a0.y, off);
            a1.x += __shfl_xor(a1.x, off); a1.y += __shfl_xor(a1.y, off);
            a2.x += __shfl_xor(a2.x, off); a2.y += __shfl_xor(a2.y, off);
            a3.x += __shfl_xor(a3.x, off); a3.y += __shfl_xor(a3.y, off);
        }
        if (valid && oct == 0) {
            float dv = dis[node];
            float v0 = fmaxf(a0.x * dv + b[8 * fl + 0], 0.f);
            float v1 = fmaxf(a0.y * dv + b[8 * fl + 1], 0.f);
            float v2 = fmaxf(a1.x * dv + b[8 * fl + 2], 0.f);
            float v3 = fmaxf(a1.y * dv + b[8 * fl + 3], 0.f);
            float v4 = fmaxf(a2.x * dv + b[8 * fl + 4], 0.f);
            float v5 = fmaxf(a2.y * dv + b[8 * fl + 5], 0.f);
            float v6 = fmaxf(a3.x * dv + b[8 * fl + 6], 0.f);
            float v7 = fmaxf(a3.y * dv + b[8 * fl + 7], 0.f);
            if (FUSE3) {
                // layer-3 projection fused: t3 = dot(h, W3) * dis
                float part = v0 * W3[8 * fl + 0] + v1 * W3[8 * fl + 1]
                           + v2 * W3[8 * fl + 2] + v3 * W3[8 * fl + 3]
                           + v4 * W3[8 * fl + 4] + v5 * W3[8 * fl + 5]
                           + v6 * W3[8 * fl + 6] + v7 * W3[8 * fl + 7];
                part += __shfl_xor(part, 1);
                part += __shfl_xor(part, 2);
                part += __shfl_xor(part, 4);
                if (fl == 0) t3[node] = part * dv;
            } else {
                uint4 p;
                p.x = f2bf(v0) | (f2bf(v1) << 16);
                p.y = f2bf(v2) | (f2bf(v3) << 16);
                p.z = f2bf(v4) | (f2bf(v5) << 16);
                p.w = f2bf(v6) | (f2bf(v7) << 16);
                ((uint4*)hb)[node * 8 + fl] = p;
            }
        }
    }
}

// ---------------------------------------------------------------------------
// Fused layer-3 aggregation + sigmoid. Wave = 8 nodes x 8 lanes; per-lane
// edge stride 8, unroll 2; shfl_xor(1,2,4) reduce within the 8-lane group.
// ---------------------------------------------------------------------------
__global__ void k_out(const float* __restrict__ t3, const int* __restrict__ rowptr,
                      const int* __restrict__ csr, const float* __restrict__ dis,
                      const float* __restrict__ b3, float* __restrict__ out) {
    int wv = blockIdx.x * 4 + (threadIdx.x >> 6);
    int lane = threadIdx.x & 63;
    int g = lane >> 3;   // node group 0..7 within wave
    int sl = lane & 7;   // sub-lane within group
    int node = wv * 8 + g;
    if (node >= NN) return;  // no barriers below: divergent return safe
    float acc = (sl == 0) ? t3[node] : 0.f;  // self-loop term
    float acc1 = 0.f;
    int e = rowptr[node] + sl, end = rowptr[node + 1];
    for (; e + 8 < end; e += 16) {
        acc += t3[csr[e]];
        acc1 += t3[csr[e + 8]];
    }
    if (e < end) acc += t3[csr[e]];
    acc += acc1;
    acc += __shfl_xor(acc, 1);
    acc += __shfl_xor(acc, 2);
    acc += __shfl_xor(acc, 4);
    if (sl == 0) {
        float z = acc * dis[node] + b3[0];
        out[node] = 1.f / (1.f + __expf(-z));
    }
}

// ---------------------------------------------------------------------------
extern "C" void kernel_launch(void* const* d_in, const int* in_sizes, int n_in,
                              void* d_out, int out_size, void* d_ws, size_t ws_size,
                              hipStream_t stream) {
    const float* x  = (const float*)d_in[0];   // N x 128
    const float* W1 = (const float*)d_in[1];   // 128 x 64
    const float* b1 = (const float*)d_in[2];   // 64
    const float* W2 = (const float*)d_in[3];   // 64 x 64
    const float* b2 = (const float*)d_in[4];   // 64
    const float* W3 = (const float*)d_in[5];   // 64 x 1
    const float* b3 = (const float*)d_in[6];   // 1
    const int*   ei = (const int*)d_in[7];     // 2 x E
    const int* src = ei;
    const int* dst = ei + NE;
    float* out = (float*)d_out;

    // Workspace layout
    unsigned short* TSB = (unsigned short*)d_ws;          // N*64 bf16 (ts)
    unsigned short* HB  = TSB + (size_t)NN * 64;          // N*64 bf16 (h)
    float* dis    = (float*)(HB + (size_t)NN * 64);       // N
    float* t3     = dis + NN;                             // N
    int*   deg    = (int*)(t3 + NN);                      // N
    int*   rowptr = deg + NN;                             // N+1 (+pad)
    int*   bsums  = rowptr + NN + 8;                      // 512
    int*   csr    = bsums + 512;                          // E
    // Aliased scratch (dead before the aliasee is first written):
    unsigned char* lrank = (unsigned char*)TSB;  // E bytes; dead before k_gemm1
    unsigned char* cnt   = (unsigned char*)HB;   // NCHUNK*NN bytes; dead before first k_agg_relu

    const int nbN = (NN + 255) / 256;       // 391
    const int nbG = (NN + 63) / 64;         // 1563
    const int nbOut = (NN + 31) / 32;       // 3125

    // CSR build + normalization (LDS counting sort, no device-scope atomics)
    k_cnt<<<NSHARD * NCHUNK, 256, 0, stream>>>((const int4*)dst, cnt, lrank);
    k_blkscan<<<nbN, 256, 0, stream>>>(cnt, deg, bsums);
    k_rowptr<<<nbN, 256, 0, stream>>>(deg, bsums, rowptr, dis);
    k_build_csr<<<2048, 256, 0, stream>>>((const int4*)src, (const int4*)dst,
                                          cnt, (const unsigned*)lrank, rowptr, csr);

    // Layer 1
    k_gemm1<<<nbG, 256, 0, stream>>>(x, W1, dis, TSB);
    k_agg_relu<false><<<AGG_BLOCKS, 256, 0, stream>>>(TSB, rowptr, csr, dis, b1, W3, HB, t3);

    // Layer 2
    k_gemm2<<<nbG, 256, 0, stream>>>(HB, W2, dis, TSB);
    k_agg_relu<true><<<AGG_BLOCKS, 256, 0, stream>>>(TSB, rowptr, csr, dis, b2, W3, HB, t3);

    // Layer 3 output
    k_out<<<nbOut, 256, 0, stream>>>(t3, rowptr, csr, dis, b3, out);
}